// Round 1
// baseline (411.820 us; speedup 1.0000x reference)
//
#include <hip/hip_runtime.h>
#include <hip/hip_bf16.h>
#include <stdint.h>

// ---------------- constants (problem shape) ----------------
#define BB 2
#define TT 2048
#define DD 2048
#define NH 16
#define KH 4
#define HD 128
#define SS 2048
#define WINDOW 1024
#define QSCALE 0.08838834764831845f  // 1/sqrt(128)

typedef __attribute__((ext_vector_type(8))) short bf16x8;
typedef __attribute__((ext_vector_type(4))) float f32x4;

#define MFMA16(a, b, c) __builtin_amdgcn_mfma_f32_16x16x32_bf16(a, b, c, 0, 0, 0)

__device__ __forceinline__ ushort f2bf(float f) {
  uint32_t u = __float_as_uint(f);
  u += 0x7FFF + ((u >> 16) & 1);
  return (ushort)(u >> 16);
}
__device__ __forceinline__ float bf2f(ushort h) {
  return __uint_as_float(((uint32_t)h) << 16);
}

__device__ __forceinline__ void async_copy16(const ushort* g, ushort* l) {
  __builtin_amdgcn_global_load_lds(
      (const __attribute__((address_space(1))) uint32_t*)g,
      (__attribute__((address_space(3))) uint32_t*)l, 16, 0, 0);
}

// ---------------- prep: per-batch start / first nonzero ----------------
__global__ void prep_kernel(const int* __restrict__ seg, const int* __restrict__ start_ind,
                            int* __restrict__ meta) {
  int b = blockIdx.x;
  __shared__ int red[256];
  int tid = threadIdx.x;
  int first = TT;
  for (int t = tid; t < TT; t += 256)
    if (seg[b * TT + t] != 0) first = min(first, t);
  red[tid] = first;
  __syncthreads();
  for (int s = 128; s > 0; s >>= 1) {
    if (tid < s) red[tid] = min(red[tid], red[tid + s]);
    __syncthreads();
  }
  if (tid == 0) {
    int fi = red[0];               // first nonzero index, TT if none
    int left_pads = fi;
    int st = start_ind[b] < 0 ? left_pads : start_ind[b];
    meta[b * 2 + 0] = st;
    meta[b * 2 + 1] = (fi >= TT) ? 0 : fi;  // argmax fallback 0
  }
}

// ---------------- fp32 -> bf16 convert ----------------
__global__ void cvt_x(const float* __restrict__ x, ushort* __restrict__ xb, int n4) {
  int i = blockIdx.x * blockDim.x + threadIdx.x;
  if (i < n4) {
    float4 v = ((const float4*)x)[i];
    ushort4 o;
    o.x = f2bf(v.x); o.y = f2bf(v.y); o.z = f2bf(v.z); o.w = f2bf(v.w);
    ((ushort4*)xb)[i] = o;
  }
}

// ---------------- fp32 [R][C] -> bf16 transpose [C][ldo] ----------------
__global__ void transpose_bf(const float* __restrict__ in, ushort* __restrict__ out,
                             int R, int C, int ldo) {
  __shared__ float tile[32][33];
  int tx = threadIdx.x & 31, ty = threadIdx.x >> 5;
  int r0 = blockIdx.y * 32, c0 = blockIdx.x * 32;
#pragma unroll
  for (int k = 0; k < 4; k++)
    tile[ty + k * 8][tx] = in[(size_t)(r0 + ty + k * 8) * C + c0 + tx];
  __syncthreads();
#pragma unroll
  for (int k = 0; k < 4; k++)
    out[(size_t)(c0 + ty + k * 8) * ldo + r0 + tx] = f2bf(tile[tx][ty + k * 8]);
}

// ---------------- GEMM: C[M][N] = A[M][K] * Bt[N][K]^T (bf16 in, fp32 acc) --------
template <int OUT_F32>
__global__ __launch_bounds__(256) void gemm_bt(const ushort* __restrict__ A,
                                               const ushort* __restrict__ Bt,
                                               void* __restrict__ Cout,
                                               int M, int N, int K) {
  __shared__ ushort As[128 * 32];
  __shared__ ushort Bs[128 * 32];
  int tid = threadIdx.x;
  int lane = tid & 63, wave = tid >> 6;
  int wr = wave >> 1, wc = wave & 1;
  int row0 = blockIdx.y * 128, col0 = blockIdx.x * 128;
  int lcol = lane & 15, quad = lane >> 4;

  f32x4 acc[4][4];
#pragma unroll
  for (int i = 0; i < 4; i++)
#pragma unroll
    for (int j = 0; j < 4; j++) {
      f32x4 z = {0.f, 0.f, 0.f, 0.f};
      acc[i][j] = z;
    }

  const ushort* Ag  = A  + (size_t)(row0 + (tid >> 2)) * K + (tid & 3) * 8;
  const ushort* Bg  = Bt + (size_t)(col0 + (tid >> 2)) * K + (tid & 3) * 8;
  const ushort* Ag2 = Ag + (size_t)64 * K;
  const ushort* Bg2 = Bg + (size_t)64 * K;
  ushort* AsP  = As + tid * 8;
  ushort* AsP2 = As + (tid + 256) * 8;
  ushort* BsP  = Bs + tid * 8;
  ushort* BsP2 = Bs + (tid + 256) * 8;

  for (int kc = 0; kc < K; kc += 32) {
    __syncthreads();
    async_copy16(Ag + kc, AsP);
    async_copy16(Ag2 + kc, AsP2);
    async_copy16(Bg + kc, BsP);
    async_copy16(Bg2 + kc, BsP2);
    __syncthreads();
    bf16x8 af[4], bf[4];
#pragma unroll
    for (int i = 0; i < 4; i++)
      af[i] = *(const bf16x8*)(As + (wr * 64 + i * 16 + lcol) * 32 + quad * 8);
#pragma unroll
    for (int j = 0; j < 4; j++)
      bf[j] = *(const bf16x8*)(Bs + (wc * 64 + j * 16 + lcol) * 32 + quad * 8);
#pragma unroll
    for (int i = 0; i < 4; i++)
#pragma unroll
      for (int j = 0; j < 4; j++)
        acc[i][j] = MFMA16(af[i], bf[j], acc[i][j]);
  }

#pragma unroll
  for (int i = 0; i < 4; i++)
#pragma unroll
    for (int j = 0; j < 4; j++) {
      int r_base = row0 + wr * 64 + i * 16 + quad * 4;
      int c = col0 + wc * 64 + j * 16 + lcol;
#pragma unroll
      for (int r = 0; r < 4; r++) {
        float v = acc[i][j][r];
        if (OUT_F32)
          ((float*)Cout)[(size_t)(r_base + r) * N + c] = v;
        else
          ((ushort*)Cout)[(size_t)(r_base + r) * N + c] = f2bf(v);
      }
    }
}

// ---------------- RoPE + scatter to head-major bf16 layouts ----------------
// Cqkv row (b,t): cols [0,2048) q, [2048,2560) k, [2560,3072) v
__global__ void rope_scatter(const ushort* __restrict__ C, const int* __restrict__ seg,
                             const int* __restrict__ cur_p, const int* __restrict__ meta,
                             ushort* __restrict__ qa, ushort* __restrict__ ka,
                             ushort* __restrict__ va) {
  int bt = blockIdx.x;
  int b = bt >> 11;
  int t = bt & 2047;
  int cur = cur_p[0];
  int first = meta[b * 2 + 1];
  int segv = seg[bt];
  int pos = (segv != 0) ? (t - first + cur) : (1 << 30);
  float posf = (float)pos;
  const ushort* row = C + (size_t)bt * 3072;

  for (int j = threadIdx.x; j < 3072; j += 256) {
    float v = bf2f(row[j]);
    int head, hh;
    bool isq = (j < 2048), isk = (j >= 2048 && j < 2560);
    if (isq)       { head = j >> 7;            hh = j & 127; }
    else if (isk)  { head = (j - 2048) >> 7;   hh = (j - 2048) & 127; }
    else           { head = (j - 2560) >> 7;   hh = (j - 2560) & 127; }
    float outv = v;
    if ((isq || isk) && hh < 64) {
      int i = hh & 31;
      float inv_freq = exp2f((float)i * -0.4152410118609203f);  // 10000^(-i/32)
      float ang = posf * inv_freq;
      float sn = sinf(ang), cs = cosf(ang);
      float partner = bf2f(row[(hh < 32) ? (j + 32) : (j - 32)]);
      outv = (hh < 32) ? (v * cs - partner * sn) : (v * cs + partner * sn);
    }
    if (isq) {
      outv *= QSCALE;
      qa[((size_t)(b * NH + head) * TT + t) * HD + hh] = f2bf(outv);
    } else if (isk) {
      ka[((size_t)(b * KH + head) * SS + t) * HD + hh] = f2bf(outv);
    } else {
      va[((size_t)(b * KH + head) * SS + t) * HD + hh] = f2bf(outv);
    }
  }
}

// ---------------- flash attention: BQ=64 (4 waves x 16 rows), BK=64 ----------------
__global__ __launch_bounds__(256) void flash_attn(
    const ushort* __restrict__ qa, const ushort* __restrict__ ka,
    const ushort* __restrict__ va, const float* __restrict__ sink_bias,
    const int* __restrict__ seg, const int* __restrict__ cur_p,
    const int* __restrict__ meta, ushort* __restrict__ Obuf) {
  int bx = blockIdx.x;
  int qt = bx & 31;
  int n = (bx >> 5) & 15;
  int b = bx >> 9;
  int kb = n >> 2;
  int t0 = qt * 64;
  int cur = cur_p[0];
  int start = meta[b * 2 + 0];

  __shared__ ushort Ks[64 * 136];   // K tile [key][h], stride 136
  __shared__ ushort VT[128 * 72];   // V tile transposed [h][key], stride 72
  __shared__ ushort Ps[4 * 16 * 72];// per-wave P [qrow][key], stride 72

  int tid = threadIdx.x, lane = tid & 63, w = tid >> 6;
  int lcol = lane & 15, quad = lane >> 4;

  const ushort* qbase = qa + (size_t)(b * NH + n) * TT * HD;
  const ushort* kbase = ka + (size_t)(b * KH + kb) * SS * HD;
  const ushort* vbase = va + (size_t)(b * KH + kb) * SS * HD;

  // Q fragments: A[m=lcol][k=quad*8+j], 4 chunks of 32 over H=128
  bf16x8 qf[4];
  {
    const ushort* qrow = qbase + (size_t)(t0 + w * 16 + lcol) * HD + quad * 8;
#pragma unroll
    for (int c = 0; c < 4; c++) qf[c] = *(const bf16x8*)(qrow + c * 32);
  }

  float m_i[4], l_i[4];
  f32x4 oacc[8];
#pragma unroll
  for (int r = 0; r < 4; r++) { m_i[r] = -1e30f; l_i[r] = 0.f; }
#pragma unroll
  for (int ob = 0; ob < 8; ob++) { f32x4 z = {0.f, 0.f, 0.f, 0.f}; oacc[ob] = z; }

  int qrow_g[4], segq[4];
#pragma unroll
  for (int r = 0; r < 4; r++) {
    qrow_g[r] = t0 + w * 16 + quad * 4 + r;
    segq[r] = seg[b * TT + qrow_g[r]];
  }

  int s_lo = cur + t0 - (WINDOW - 1); if (s_lo < 0) s_lo = 0;
  int s_hi = cur + t0 + 63;           if (s_hi > SS - 1) s_hi = SS - 1;

  for (int kt = (s_lo >> 6); kt <= (s_hi >> 6); kt++) {
    int ks0 = kt * 64;
    __syncthreads();
    // stage K tile: 64x128, 16B chunks
#pragma unroll
    for (int p = 0; p < 4; p++) {
      int idx = tid + p * 256;
      int rr = idx >> 4, c8 = (idx & 15) * 8;
      uint4 d = *(const uint4*)(kbase + (size_t)(ks0 + rr) * HD + c8);
      *(uint4*)(Ks + rr * 136 + c8) = d;
    }
    // stage V transposed
#pragma unroll
    for (int p = 0; p < 4; p++) {
      int idx = tid + p * 256;
      int sv_ = idx & 63, h8 = (idx >> 6) * 8;
      union { uint4 u; ushort us[8]; } tmp;
      tmp.u = *(const uint4*)(vbase + (size_t)(ks0 + sv_) * HD + h8);
#pragma unroll
      for (int e = 0; e < 8; e++) VT[(h8 + e) * 72 + sv_] = tmp.us[e];
    }
    __syncthreads();

    // S = Q K^T : 4 col-blocks of 16 keys
    f32x4 sacc[4];
#pragma unroll
    for (int cb = 0; cb < 4; cb++) { f32x4 z = {0.f, 0.f, 0.f, 0.f}; sacc[cb] = z; }
#pragma unroll
    for (int c = 0; c < 4; c++) {
#pragma unroll
      for (int cb = 0; cb < 4; cb++) {
        bf16x8 kf = *(const bf16x8*)(Ks + (cb * 16 + lcol) * 136 + c * 32 + quad * 8);
        sacc[cb] = MFMA16(qf[c], kf, sacc[cb]);
      }
    }

    // mask + online softmax (rows quad*4+r, cols lcol within each 16-block)
#pragma unroll
    for (int r = 0; r < 4; r++) {
      int qp = cur + qrow_g[r];
      float mx = m_i[r];
      float sv[4];
#pragma unroll
      for (int cb = 0; cb < 4; cb++) {
        int s_idx = ks0 + cb * 16 + lcol;
        int kvseg = (s_idx >= start && s_idx < cur + TT) ? 1 : 0;
        bool valid = (s_idx <= qp) && (s_idx >= qp - (WINDOW - 1)) && (kvseg == segq[r]);
        float v = valid ? sacc[cb][r] : -1e30f;
        sv[cb] = v;
        mx = fmaxf(mx, v);
      }
#pragma unroll
      for (int off = 1; off < 16; off <<= 1) mx = fmaxf(mx, __shfl_xor(mx, off));
      float alpha = __expf(m_i[r] - mx);
      m_i[r] = mx;
      float rs = 0.f;
#pragma unroll
      for (int cb = 0; cb < 4; cb++) {
        float p = (sv[cb] > -1e29f) ? __expf(sv[cb] - mx) : 0.f;
        Ps[(w * 16 + quad * 4 + r) * 72 + cb * 16 + lcol] = f2bf(p);
        rs += p;
      }
#pragma unroll
      for (int off = 1; off < 16; off <<= 1) rs += __shfl_xor(rs, off);
      l_i[r] = l_i[r] * alpha + rs;
#pragma unroll
      for (int ob = 0; ob < 8; ob++) oacc[ob][r] *= alpha;
    }
    __syncthreads();  // make P visible (conservative; per-wave region)

    // O += P V
#pragma unroll
    for (int c2 = 0; c2 < 2; c2++) {
      bf16x8 pf = *(const bf16x8*)(Ps + (w * 16 + lcol) * 72 + c2 * 32 + quad * 8);
#pragma unroll
      for (int ob = 0; ob < 8; ob++) {
        bf16x8 vf = *(const bf16x8*)(VT + (ob * 16 + lcol) * 72 + c2 * 32 + quad * 8);
        oacc[ob] = MFMA16(pf, vf, oacc[ob]);
      }
    }
  }

  float sb = sink_bias[n];
#pragma unroll
  for (int r = 0; r < 4; r++) {
    float l = l_i[r] + __expf(sb - m_i[r]);  // sink in denominator
    float inv = 1.f / l;
    int t = qrow_g[r];
    size_t base = ((size_t)(b * TT + t)) * (NH * HD) + n * HD;
#pragma unroll
    for (int ob = 0; ob < 8; ob++)
      Obuf[base + ob * 16 + lcol] = f2bf(oacc[ob][r] * inv);
  }
}

// ---------------- launch ----------------
extern "C" void kernel_launch(void* const* d_in, const int* in_sizes, int n_in,
                              void* d_out, int out_size, void* d_ws, size_t ws_size,
                              hipStream_t stream) {
  const float* x  = (const float*)d_in[0];
  const float* wq = (const float*)d_in[1];
  const float* wk = (const float*)d_in[2];
  const float* wv = (const float*)d_in[3];
  const float* wo = (const float*)d_in[4];
  const float* sink = (const float*)d_in[5];
  // d_in[6], d_in[7]: k_cache/v_cache — fully overwritten (cur_ind=0, T=S), unused
  const int* seg = (const int*)d_in[8];
  const int* cur = (const int*)d_in[9];
  const int* start_ind = (const int*)d_in[10];

  char* ws = (char*)d_ws;
  ushort* xb    = (ushort*)(ws + 0);                   // 16 MB
  ushort* WcatT = (ushort*)(ws + 16777216);            // 12 MB  [col 0..3071][k 0..2047]
  ushort* WoT   = (ushort*)(ws + 29360128);            // 8 MB   [d][n*128+v]
  ushort* Cqkv  = (ushort*)(ws + 37748736);            // 24 MB  [b*T+t][3072]
  ushort* Obuf  = Cqkv;                                // alias (Cqkv dead after rope)
  ushort* qa    = (ushort*)(ws + 62914560);            // 16 MB  [b,n][t][h]
  ushort* ka    = (ushort*)(ws + 79691776);            // 4 MB   [b,kb][s][h]
  ushort* va    = (ushort*)(ws + 83886080);            // 4 MB
  int*    meta  = (int*)(ws + 88080384);               // start[b], first_idx[b]

  prep_kernel<<<BB, 256, 0, stream>>>(seg, start_ind, meta);
  cvt_x<<<8192, 256, 0, stream>>>(x, xb, (BB * TT * DD) / 4);
  transpose_bf<<<dim3(64, 64), 256, 0, stream>>>(wq, WcatT, 2048, 2048, 2048);
  transpose_bf<<<dim3(16, 64), 256, 0, stream>>>(wk, WcatT + (size_t)2048 * 2048, 2048, 512, 2048);
  transpose_bf<<<dim3(16, 64), 256, 0, stream>>>(wv, WcatT + (size_t)2560 * 2048, 2048, 512, 2048);
  transpose_bf<<<dim3(64, 64), 256, 0, stream>>>(wo, WoT, 2048, 2048, 2048);
  gemm_bt<0><<<dim3(24, 32), 256, 0, stream>>>(xb, WcatT, Cqkv, 4096, 3072, 2048);
  rope_scatter<<<4096, 256, 0, stream>>>(Cqkv, seg, cur, meta, qa, ka, va);
  flash_attn<<<1024, 256, 0, stream>>>(qa, ka, va, sink, seg, cur, meta, Obuf);
  gemm_bt<1><<<dim3(16, 32), 256, 0, stream>>>(Obuf, WoT, d_out, 4096, 2048, 2048);
}